// Round 7
// baseline (298.665 us; speedup 1.0000x reference)
//
#include <hip/hip_runtime.h>
#include <stdint.h>

#define BATCH 256
#define NV 10475
#define NVP 10496        // NV padded to 164 tiles of 64
#define NJ 55
#define PB 486           // (NJ-1)*9
#define KS 506           // PB + 10 betas + 10 exprs
#define VC (NV*3)        // 31425
#define KP 512           // K padded to 16 chunks of 32
#define BKC 32
#define NCHUNK 16
#define BN 64
#define JCH 8
#define JCHUNK 1312      // 8*1312 >= NV

typedef short bf16x8 __attribute__((ext_vector_type(8)));
typedef float f32x4  __attribute__((ext_vector_type(4)));

__constant__ int c_parents[NJ] = {
  -1,0,0,0,1,2,3,4,5,6,7,8,9,9,9,12,13,14,16,17,18,19,15,15,15,
  20,25,26,20,28,29,20,31,32,20,34,35,20,37,38,21,40,41,21,43,44,
  21,46,47,21,49,50,21,52,53};

// tree depth of each joint (max 10)
__constant__ int c_depth[NJ] = {
  0,1,1,1,2,2,2,3,3,3,4,4,4,4,4,5,5,5,6,6,7,7,6,6,6,
  8,9,10,8,9,10,8,9,10,8,9,10,8,9,10,
  8,9,10,8,9,10,8,9,10,8,9,10,8,9,10};

__device__ __forceinline__ unsigned short f2bf(float x){   // RNE fp32->bf16
  uint32_t u = __float_as_uint(x);
  uint32_t r = (u + 0x7fffu + ((u >> 16) & 1u)) >> 16;
  return (unsigned short)r;
}
__device__ __forceinline__ float bf2f(unsigned short h){
  return __uint_as_float(((uint32_t)h) << 16);
}

// ---------------- prep: lw -> bf16 hi/lo [NVP][64]; sd/ed -> fp32 [20][VC] --
__global__ __launch_bounds__(256) void k_prep(
    const float* __restrict__ lw, const float* __restrict__ sd,
    const float* __restrict__ ed, unsigned short* __restrict__ lwb,
    float* __restrict__ sdedT) {
  int bid = blockIdx.x;
  const int LWB_BLOCKS = (NVP*64)/256;     // 2624
  if (bid < LWB_BLOCKS) {
    int idx = bid*256 + threadIdx.x;       // n*64 + j
    int n = idx >> 6, j = idx & 63;
    float v = (n < NV && j < NJ) ? lw[(size_t)n*NJ + j] : 0.f;
    unsigned short hi = f2bf(v);
    float lo = v - bf2f(hi);
    lwb[idx] = hi;
    lwb[(size_t)NVP*64 + idx] = f2bf(lo);
  } else {
    int idx = (bid - LWB_BLOCKS)*256 + threadIdx.x;   // r*VC + col
    if (idx >= 20*VC) return;
    int r = idx / VC, col = idx - r*VC;
    int n = col/3, c = col - n*3;
    float v = (r < 10) ? sd[(size_t)n*30 + c*10 + r]
                       : ed[(size_t)n*30 + c*10 + (r-10)];
    sdedT[idx] = v;
  }
}

// ---------------- full_pose gather helper ----------------------------------
__device__ __forceinline__ const float* pose_src(int j, int b,
    const float* wrot, const float* bpose, const float* jaw, const float* leye,
    const float* reye, const float* lhand, const float* rhand) {
  if (j==0)  return wrot  + b*9;
  if (j<=21) return bpose + (b*21 + (j-1))*9;
  if (j==22) return jaw   + b*9;
  if (j==23) return leye  + b*9;
  if (j==24) return reye  + b*9;
  if (j<=39) return lhand + (b*15 + (j-25))*9;
  return rhand + (b*15 + (j-40))*9;
}

// ------- A-matrix for big GEMM: [pose_feature(486) | bs(10) | es(10) | 0] ---
__global__ __launch_bounds__(512) void k_posefeat(
    const float* __restrict__ bpose, const float* __restrict__ jaw,
    const float* __restrict__ leye, const float* __restrict__ reye,
    const float* __restrict__ lhand, const float* __restrict__ rhand,
    const float* __restrict__ bs, const float* __restrict__ es,
    unsigned short* __restrict__ pfb) {
  int b = blockIdx.x, t = threadIdx.x;     // t < 512
  unsigned short o = 0;
  if (t < PB){
    int jj = t/9, rc = t - jj*9;
    const float* rs = pose_src(jj+1, b, nullptr, bpose, jaw, leye, reye, lhand, rhand);
    float v = rs[rc];
    if (rc==0 || rc==4 || rc==8) v -= 1.0f;
    o = f2bf(v);
  } else if (t < 496){
    o = f2bf(bs[b*10 + (t-486)]);
  } else if (t < KS){
    o = f2bf(es[b*10 + (t-496)]);
  }
  pfb[(size_t)b*KP + t] = o;
}

// ---------------- JS = Jreg @ [sd | ed | vt] : per-(joint,chunk) partials ---
__global__ __launch_bounds__(256) void k_jsmall(
    const float* __restrict__ jreg, const float* __restrict__ sd,
    const float* __restrict__ ed, const float* __restrict__ vt,
    float* __restrict__ part) {
  int ch = blockIdx.x, j = blockIdx.y;
  int t = threadIdx.x;
  float acc[63];
  #pragma unroll
  for (int s=0;s<63;s++) acc[s]=0.f;
  int n0 = ch*JCHUNK, nend = min(n0+JCHUNK, NV);
  for (int n = n0 + t; n < nend; n += 256){
    float w = jreg[(size_t)j*NV + n];
    const float* sp = sd + (size_t)n*30;
    const float* ep = ed + (size_t)n*30;
    const float* vp = vt + (size_t)n*3;
    #pragma unroll
    for (int c=0;c<3;c++){
      #pragma unroll
      for (int q=0;q<10;q++){
        acc[c*21+q]    += w*sp[c*10+q];
        acc[c*21+10+q] += w*ep[c*10+q];
      }
      acc[c*21+20] += w*vp[c];
    }
  }
  #pragma unroll
  for (int s=0;s<63;s++){
    float a = acc[s];
    #pragma unroll
    for (int d=32; d>=1; d>>=1) a += __shfl_xor(a,d);
    acc[s]=a;
  }
  __shared__ float red[4][63];
  int w = t>>6, l = t&63;
  if (l==0){
    #pragma unroll
    for (int s=0;s<63;s++) red[w][s]=acc[s];
  }
  __syncthreads();
  if (t < 63){
    float a = red[0][t]+red[1][t]+red[2][t]+red[3][t];
    part[((size_t)j*JCH+ch)*63 + t] = a;
  }
}

// ---------------- joints[b][j][c] from JS partials + betas ------------------
__global__ __launch_bounds__(192) void k_joints2(
    const float* __restrict__ part, const float* __restrict__ bs,
    const float* __restrict__ es, float* __restrict__ joints) {
  int b = blockIdx.x, t = threadIdx.x;
  if (t >= NJ*3) return;
  int j = t/3, c = t - j*3;
  float S[21];
  #pragma unroll
  for (int q=0;q<21;q++) S[q]=0.f;
  for (int ch=0; ch<JCH; ch++){
    const float* p = part + ((size_t)j*JCH+ch)*63 + c*21;
    #pragma unroll
    for (int q=0;q<21;q++) S[q] += p[q];
  }
  float a = S[20];
  #pragma unroll
  for (int q=0;q<10;q++) a += S[q]*bs[b*10+q] + S[10+q]*es[b*10+q];
  joints[(size_t)b*NJ*3 + t] = a;
}

// ------- kinematic chain via wave-level tree scan (lane j = joint j) --------
// One wave per batch; chain matrices live in registers; parents via __shfl.
__global__ __launch_bounds__(256) void k_chain(
    const float* __restrict__ wrot, const float* __restrict__ bpose,
    const float* __restrict__ jaw, const float* __restrict__ leye,
    const float* __restrict__ reye, const float* __restrict__ lhand,
    const float* __restrict__ rhand, const float* __restrict__ wtsl,
    const float* __restrict__ joints,
    unsigned short* __restrict__ arelb, float* __restrict__ jout) {
  const int w = threadIdx.x >> 6, lane = threadIdx.x & 63;
  const int b = blockIdx.x*4 + w;
  const int j = lane;
  const bool act = (j < NJ);

  // local rotation
  float R[9] = {1.f,0.f,0.f, 0.f,1.f,0.f, 0.f,0.f,1.f};
  if (act){
    const float* rs = pose_src(j, b, wrot, bpose, jaw, leye, reye, lhand, rhand);
    #pragma unroll
    for (int i=0;i<9;i++) R[i]=rs[i];
  }
  // joint position (lane-resident), parent via shuffle
  float jx=0.f, jy=0.f, jz=0.f;
  if (act){
    const float* jb = joints + (size_t)b*NJ*3 + j*3;
    jx=jb[0]; jy=jb[1]; jz=jb[2];
  }
  int par = act ? c_parents[j] : 0;
  if (par < 0) par = 0;
  float px = __shfl(jx, par), py = __shfl(jy, par), pz = __shfl(jz, par);
  float t0, t1, t2;
  if (j == 0){ t0=jx; t1=jy; t2=jz; }
  else       { t0=jx-px; t1=jy-py; t2=jz-pz; }

  // M starts as local [R|t]; becomes global at round == depth
  float M[12];
  #pragma unroll
  for (int r=0;r<3;r++){
    M[r*4+0]=R[r*3+0]; M[r*4+1]=R[r*3+1]; M[r*4+2]=R[r*3+2]; M[r*4+3]= (r==0?t0:(r==1?t1:t2));
  }
  int dep = act ? c_depth[j] : 99;

  #pragma unroll
  for (int L=1; L<=10; L++){
    float pm[12];
    #pragma unroll
    for (int i=0;i<12;i++) pm[i] = __shfl(M[i], par);   // exec-uniform
    if (dep == L){
      #pragma unroll
      for (int r=0;r<3;r++){
        float p0=pm[r*4+0], p1=pm[r*4+1], p2=pm[r*4+2], p3=pm[r*4+3];
        M[r*4+0] = p0*R[0]+p1*R[3]+p2*R[6];
        M[r*4+1] = p0*R[1]+p1*R[4]+p2*R[7];
        M[r*4+2] = p0*R[2]+p1*R[5]+p2*R[8];
        M[r*4+3] = p0*t0 + p1*t1 + p2*t2 + p3;
      }
    }
  }

  float wx=wtsl[b*3+0], wy=wtsl[b*3+1], wz=wtsl[b*3+2];
  if (act){
    jout[((size_t)b*NJ+j)*3+0] = M[3]  + wx;
    jout[((size_t)b*NJ+j)*3+1] = M[7]  + wy;
    jout[((size_t)b*NJ+j)*3+2] = M[11] + wz;
  }
  // A_rel with t-correction; bf16 hi/lo split; pads (lanes>=55, e>=12) zeroed
  float A[12];
  #pragma unroll
  for (int r=0;r<3;r++){
    A[r*4+0]=M[r*4+0]; A[r*4+1]=M[r*4+1]; A[r*4+2]=M[r*4+2];
    A[r*4+3]=M[r*4+3] - (M[r*4+0]*jx + M[r*4+1]*jy + M[r*4+2]*jz);
  }
  unsigned short* ah = arelb + (size_t)(b*2+0)*16*64;
  unsigned short* al = arelb + (size_t)(b*2+1)*16*64;
  #pragma unroll
  for (int e=0;e<16;e++){
    float v = (e < 12 && act) ? A[e] : 0.f;
    unsigned short hi = f2bf(v);
    float lo = v - bf2f(hi);
    ah[e*64 + j] = hi;                 // contiguous across lanes per e
    al[e*64 + j] = f2bf(lo);
  }
}

// -------- v_posed = [pf|bs|es] @ [posedirs; sdT; edT] + vt  (bf16 MFMA) -----
// Barrier-free: B-fragments loaded DIRECTLY from global (8 strided dwords
// per frag = the exact MFMA B layout: lane(m16,quad) holds B[k=quad*8+j][col]).
// One block = 4 waves covers ALL 256 batches x 64 cols -> pd read once.
__global__ __launch_bounds__(256, 2) void k_vposed(
    const float* __restrict__ pd, const float* __restrict__ sdedT,
    const float* __restrict__ vt, const unsigned short* __restrict__ pfb,
    float* __restrict__ vsh) {
  const int tid  = threadIdx.x;
  const int w    = tid >> 6, lane = tid & 63;
  const int m16  = lane & 15, quad = lane >> 4;
  const int col0 = blockIdx.x * BN;

  f32x4 acc[4][4];
  #pragma unroll
  for (int i=0;i<4;i++)
    #pragma unroll
    for (int j=0;j<4;j++) acc[i][j] = (f32x4){0.f,0.f,0.f,0.f};

  // clamped B columns (cols >= VC read col VC-1; their acc is never stored)
  int bcol[4];
  #pragma unroll
  for (int ni=0;ni<4;ni++) bcol[ni] = min(col0 + ni*16 + m16, VC-1);

  const unsigned short* pfa = pfb + (size_t)(w*64 + m16)*KP + quad*8;

  // chunks 0..14: pure posedirs rows (k0+quad*8+7 <= 479 < 486)
  #pragma unroll 2
  for (int c=0; c<15; c++){
    const int k0 = c*BKC;
    bf16x8 a[4];
    #pragma unroll
    for (int mi=0;mi<4;mi++)
      a[mi] = *((const bf16x8*)(pfa + (size_t)mi*16*KP + k0));
    union { bf16x8 v; unsigned short s[8]; } bb[4];
    #pragma unroll
    for (int ni=0;ni<4;ni++){
      #pragma unroll
      for (int j=0;j<8;j++){
        int kk = k0 + quad*8 + j;
        bb[ni].s[j] = f2bf(pd[(size_t)kk*VC + bcol[ni]]);
      }
    }
    #pragma unroll
    for (int mi=0;mi<4;mi++)
      #pragma unroll
      for (int ni=0;ni<4;ni++)
        acc[mi][ni] = __builtin_amdgcn_mfma_f32_16x16x32_bf16(
                          a[mi], bb[ni].v, acc[mi][ni], 0, 0, 0);
  }
  // chunk 15: rows 480..485 pd, 486..505 sdedT, 506..511 zero
  {
    const int k0 = 15*BKC;
    bf16x8 a[4];
    #pragma unroll
    for (int mi=0;mi<4;mi++)
      a[mi] = *((const bf16x8*)(pfa + (size_t)mi*16*KP + k0));
    union { bf16x8 v; unsigned short s[8]; } bb[4];
    #pragma unroll
    for (int ni=0;ni<4;ni++){
      #pragma unroll
      for (int j=0;j<8;j++){
        int kk = k0 + quad*8 + j;
        float f = 0.f;
        if (kk < PB)      f = pd[(size_t)kk*VC + bcol[ni]];
        else if (kk < KS) f = sdedT[(size_t)(kk-PB)*VC + bcol[ni]];
        bb[ni].s[j] = f2bf(f);
      }
    }
    #pragma unroll
    for (int mi=0;mi<4;mi++)
      #pragma unroll
      for (int ni=0;ni<4;ni++)
        acc[mi][ni] = __builtin_amdgcn_mfma_f32_16x16x32_bf16(
                          a[mi], bb[ni].v, acc[mi][ni], 0, 0, 0);
  }
  // epilogue: vsh[row][col] = acc + v_template[col]
  #pragma unroll
  for (int mi=0;mi<4;mi++){
    int rbase = w*64 + mi*16 + quad*4;
    #pragma unroll
    for (int ni=0;ni<4;ni++){
      int col = col0 + ni*16 + m16;
      if (col < VC){
        float vtc = vt[col];
        #pragma unroll
        for (int r=0;r<4;r++)
          vsh[(size_t)(rbase + r)*VC + col] = acc[mi][ni][r] + vtc;
      }
    }
  }
}

// -------- skinning via transposed MFMA: D[e][vert] = arel(16e x 64j) @ lw^T --
// A-frag = arel (e-major, exact A layout); B-frag = lw (vert-major, exact B
// layout). Lane (quad=q, m16=v) ends with T row q of vertex v in its 4 acc
// regs -> per-lane epilogue, NO LDS, no barrier, no transpose.
__global__ __launch_bounds__(256) void k_verts(
    const unsigned short* __restrict__ lwb, const unsigned short* __restrict__ arelb,
    const float* __restrict__ wtsl, float* __restrict__ out) {
  const int tid = threadIdx.x, w = tid >> 6, lane = tid & 63;
  const int m16 = lane & 15, quad = lane >> 4;
  const int n = blockIdx.x*64 + w*16 + m16;     // this lane's vertex (< NVP)
  const int b0 = blockIdx.y*16;

  // B fragments (lw): lane holds B[k=quad*8+j][n]; hi/lo x 2 k-chunks
  bf16x8 wh[2], wl[2];
  #pragma unroll
  for (int kc=0;kc<2;kc++){
    wh[kc] = *((const bf16x8*)(lwb + (size_t)n*64 + kc*32 + quad*8));
    wl[kc] = *((const bf16x8*)(lwb + (size_t)NVP*64 + (size_t)n*64 + kc*32 + quad*8));
  }
  const bool vok = (n < NV) && (quad < 3);

  #pragma unroll 2
  for (int bi=0; bi<16; bi++){
    int b = b0 + bi;
    const unsigned short* ah = arelb + (size_t)(b*2+0)*16*64;
    const unsigned short* al = arelb + (size_t)(b*2+1)*16*64;
    bf16x8 Ah[2], Al[2];
    #pragma unroll
    for (int kc=0;kc<2;kc++){
      Ah[kc] = *((const bf16x8*)(ah + m16*64 + kc*32 + quad*8));
      Al[kc] = *((const bf16x8*)(al + m16*64 + kc*32 + quad*8));
    }
    f32x4 acc = (f32x4){0.f,0.f,0.f,0.f};
    #pragma unroll
    for (int kc=0;kc<2;kc++){
      acc = __builtin_amdgcn_mfma_f32_16x16x32_bf16(Ah[kc], wh[kc], acc, 0,0,0);
      acc = __builtin_amdgcn_mfma_f32_16x16x32_bf16(Al[kc], wh[kc], acc, 0,0,0);
      acc = __builtin_amdgcn_mfma_f32_16x16x32_bf16(Ah[kc], wl[kc], acc, 0,0,0);
    }
    if (vok){
      float* op = out + ((size_t)b*NV + n)*3;
      float x = op[0], y = op[1], z = op[2];        // all lanes read before
      float o = acc[0]*x + acc[1]*y + acc[2]*z + acc[3] + wtsl[b*3+quad];
      op[quad] = o;                                  // ...any lane writes
    }
  }
}

extern "C" void kernel_launch(void* const* d_in, const int* in_sizes, int n_in,
                              void* d_out, int out_size, void* d_ws, size_t ws_size,
                              hipStream_t stream) {
  const float* wrot   = (const float*)d_in[0];
  const float* wtsl   = (const float*)d_in[1];
  const float* bshape = (const float*)d_in[2];
  const float* bpose  = (const float*)d_in[3];
  const float* lhand  = (const float*)d_in[4];
  const float* rhand  = (const float*)d_in[5];
  const float* eshape = (const float*)d_in[6];
  const float* jaw    = (const float*)d_in[7];
  const float* leye   = (const float*)d_in[8];
  const float* reye   = (const float*)d_in[9];
  const float* vt     = (const float*)d_in[10];
  const float* sd     = (const float*)d_in[11];
  const float* ed     = (const float*)d_in[12];
  const float* pd     = (const float*)d_in[13];
  const float* jreg   = (const float*)d_in[14];
  const float* lw     = (const float*)d_in[15];
  float* out = (float*)d_out;

  float* vsh  = out;                               // verts region = v_posed scratch
  float* jout = out + (size_t)BATCH*NV*3;

  float* ws     = (float*)d_ws;                    // ~7 MB total
  float* joints = ws;                                      // 256*165   = 42240
  float* part   = joints + (size_t)BATCH*NJ*3;             // 55*8*63   = 27720
  float* sdedT  = part   + (size_t)NJ*JCH*63;              // 20*VC     = 628500
  unsigned short* pfb   = (unsigned short*)(sdedT + (size_t)20*VC);   // 256*512
  unsigned short* lwb   = pfb + (size_t)BATCH*KP;                     // 2*NVP*64
  unsigned short* arelb = lwb + (size_t)2*NVP*64;                     // 256*2*16*64

  const int PREP_BLOCKS = (NVP*64)/256 + (20*VC + 255)/256;   // 2624 + 2456

  k_prep    <<<PREP_BLOCKS, 256, 0, stream>>>(lw, sd, ed, lwb, sdedT);
  k_posefeat<<<BATCH, 512, 0, stream>>>(bpose, jaw, leye, reye, lhand, rhand,
                                        bshape, eshape, pfb);
  k_jsmall  <<<dim3(JCH, NJ), 256, 0, stream>>>(jreg, sd, ed, vt, part);
  k_joints2 <<<BATCH, 192, 0, stream>>>(part, bshape, eshape, joints);
  k_chain   <<<64, 256, 0, stream>>>(wrot, bpose, jaw, leye, reye, lhand, rhand,
                                     wtsl, joints, arelb, jout);
  k_vposed  <<<(VC+BN-1)/BN, 256, 0, stream>>>(pd, sdedT, vt, pfb, vsh);
  k_verts   <<<dim3(NVP/64, 16), 256, 0, stream>>>(lwb, arelb, wtsl, out);
}